// Round 1
// baseline (519.926 us; speedup 1.0000x reference)
//
#include <hip/hip_runtime.h>

typedef __attribute__((ext_vector_type(8))) short s16x8;
typedef __attribute__((ext_vector_type(4))) short s16x4;
typedef __attribute__((ext_vector_type(4))) float f32x4;
typedef __attribute__((ext_vector_type(8))) __bf16 bf16x8;

// fp32 -> bf16 round-to-nearest-even (bit trick; all values finite here)
__device__ __forceinline__ short f2b(float f) {
  unsigned u = __float_as_uint(f);
  u += 0x7fffu + ((u >> 16) & 1u);
  return (short)(u >> 16);
}

__device__ __forceinline__ f32x4 mfma_bf16(s16x8 a, s16x8 b, f32x4 c) {
  return __builtin_amdgcn_mfma_f32_16x16x32_bf16(
      __builtin_bit_cast(bf16x8, a), __builtin_bit_cast(bf16x8, b), c, 0, 0, 0);
}

// ---------------- convert fp32 -> bf16 (x, Wq|Wk|Wv concat, Wo) ----------------
__global__ __launch_bounds__(256) void convert_all(
    const float* __restrict__ x, const float* __restrict__ wq,
    const float* __restrict__ wk, const float* __restrict__ wv,
    const float* __restrict__ wo, short* __restrict__ xb,
    short* __restrict__ wqkvb, short* __restrict__ wob) {
  size_t i4 = ((size_t)blockIdx.x * 256 + threadIdx.x) * 4;
  const float* src;
  short* dst;
  size_t off;
  if (i4 < 8388608) {
    src = x; dst = xb; off = i4;
  } else if (i4 < 9437184) {
    src = wq; dst = wqkvb; off = i4 - 8388608;
  } else if (i4 < 10485760) {
    src = wk; dst = wqkvb + 1048576; off = i4 - 9437184;
  } else if (i4 < 11534336) {
    src = wv; dst = wqkvb + 2097152; off = i4 - 10485760;
  } else {
    src = wo; dst = wob; off = i4 - 11534336;
  }
  float4 f = *(const float4*)(src + off);
  s16x4 o;
  o[0] = f2b(f.x); o[1] = f2b(f.y); o[2] = f2b(f.z); o[3] = f2b(f.w);
  *(s16x4*)(dst + off) = o;
}

// ---------------- GEMM: C[M,N] = A[M,K] * B[N,K]^T  (bf16 in, m97 structure) ----
// 128x128 block tile, BK=32, 4 waves (2x2), each wave 64x64 = 4x4 MFMA 16x16x32.
__device__ __forceinline__ void stage_tile(const short* __restrict__ g, int ld,
                                           int row0, int k0, short* lds,
                                           int wid, int lane) {
#pragma unroll
  for (int i = 0; i < 2; ++i) {
    int e = i * 2048 + wid * 512 + lane * 8;  // element index in 128x32 tile
    int row = e >> 5, col = e & 31;
    const short* gp = g + (size_t)(row0 + row) * ld + k0 + col;
    __builtin_amdgcn_global_load_lds(
        (const __attribute__((address_space(1))) void*)gp,
        (__attribute__((address_space(3))) void*)(lds + i * 2048 + wid * 512),
        16, 0, 0);
  }
}

template <int EPI>  // 0 = scatter QKV as bf16 [3][B,H,T,D]; 1 = fp32 direct store
__global__ __launch_bounds__(256) void gemm_bt(
    const short* __restrict__ A, const short* __restrict__ Bw,
    float* __restrict__ outf, short* __restrict__ qkv,
    int M, int N, int K) {
  __shared__ __align__(16) short lA[128 * 32];
  __shared__ __align__(16) short lB[128 * 32];
  const int tid = threadIdx.x;
  const int lane = tid & 63, wid = tid >> 6;
  const int quad = lane >> 4, ln15 = lane & 15;
  const int wm = wid & 1, wn = wid >> 1;
  const int m0 = blockIdx.y * 128, n0 = blockIdx.x * 128;

  f32x4 acc[4][4] = {};

  stage_tile(A, K, m0, 0, lA, wid, lane);
  stage_tile(Bw, K, n0, 0, lB, wid, lane);

  const int nk = K >> 5;
  for (int kt = 0; kt < nk; ++kt) {
    __syncthreads();  // drains vmcnt before barrier -> staged tile visible
    s16x8 af[4], bf[4];
#pragma unroll
    for (int i = 0; i < 4; ++i)
      af[i] = *(const s16x8*)&lA[(wm * 64 + i * 16 + ln15) * 32 + quad * 8];
#pragma unroll
    for (int j = 0; j < 4; ++j)
      bf[j] = *(const s16x8*)&lB[(wn * 64 + j * 16 + ln15) * 32 + quad * 8];
#pragma unroll
    for (int i = 0; i < 4; ++i)
#pragma unroll
      for (int j = 0; j < 4; ++j)
        acc[i][j] = mfma_bf16(af[i], bf[j], acc[i][j]);
    __syncthreads();  // all waves done reading before overwrite
    if (kt + 1 < nk) {
      stage_tile(A, K, m0, (kt + 1) << 5, lA, wid, lane);
      stage_tile(Bw, K, n0, (kt + 1) << 5, lB, wid, lane);
    }
  }

  // C/D layout (verified m89/m91): row(m) = quad*4 + r, col(n) = lane&15
#pragma unroll
  for (int i = 0; i < 4; ++i)
#pragma unroll
    for (int j = 0; j < 4; ++j)
#pragma unroll
      for (int r = 0; r < 4; ++r) {
        int m = m0 + wm * 64 + i * 16 + quad * 4 + r;
        int n = n0 + wn * 64 + j * 16 + ln15;
        float v = acc[i][j][r];
        if (EPI == 1) {
          outf[(size_t)m * N + n] = v;
        } else {
          int b = m >> 11, t = m & 2047;
          int which = n >> 10, rem = n & 1023;
          int h = rem >> 6, d = rem & 63;
          qkv[(size_t)which * 8388608 +
              (size_t)((((b << 4) + h) << 11) + t) * 64 + d] = f2b(v);
        }
      }
}

// ---------------- flash attention, causal, per (b,h) -----------------------
// Block: 256 thr = 4 waves; 64 Q rows per block (16 per wave); K/V tiles of 64.
// LDS padded to 72 cols -> 2-way bank aliasing only (free per m136).
__global__ __launch_bounds__(256) void attn_fa(
    const short* __restrict__ Q, const short* __restrict__ K,
    const short* __restrict__ V, short* __restrict__ Aout) {
  __shared__ __align__(16) short sQ[64 * 72];
  __shared__ __align__(16) short sK[64 * 72];
  __shared__ __align__(16) short sVt[64 * 72];
  __shared__ __align__(16) short sP[4 * 16 * 72];
  const int tid = threadIdx.x;
  const int lane = tid & 63, wid = tid >> 6;
  const int quad = lane >> 4, ln15 = lane & 15;
  const int qt = blockIdx.x, bh = blockIdx.y;
  const int q0 = qt * 64;
  const short* Qb = Q + (size_t)bh * 131072;
  const short* Kb = K + (size_t)bh * 131072;
  const short* Vb = V + (size_t)bh * 131072;

  // stage Q tile [64][64] -> sQ [64][72]
#pragma unroll
  for (int i = 0; i < 2; ++i) {
    int c = tid + i * 256;
    int row = c >> 3, col = (c & 7) * 8;
    *(s16x8*)&sQ[row * 72 + col] = *(const s16x8*)&Qb[(q0 + row) * 64 + col];
  }
  __syncthreads();
  // A-frag (m120): A[m=lane&15][k=quad*8+j]; wave wid owns q rows wid*16..+16
  s16x8 qf0 = *(const s16x8*)&sQ[(wid * 16 + ln15) * 72 + quad * 8];
  s16x8 qf1 = *(const s16x8*)&sQ[(wid * 16 + ln15) * 72 + 32 + quad * 8];

  f32x4 o[4] = {};
  float mrun[4], lrun[4];
#pragma unroll
  for (int r = 0; r < 4; ++r) { mrun[r] = -1e30f; lrun[r] = 0.f; }

  short* sPw = sP + wid * 16 * 72;
  const int nt = qt + 1;
  for (int kt = 0; kt < nt; ++kt) {
    __syncthreads();  // prior iteration's LDS reads complete
    // stage K tile [64][64] -> sK [64][72]
#pragma unroll
    for (int i = 0; i < 2; ++i) {
      int c = tid + i * 256;
      int row = c >> 3, col = (c & 7) * 8;
      *(s16x8*)&sK[row * 72 + col] = *(const s16x8*)&Kb[(kt * 64 + row) * 64 + col];
    }
    // stage V transposed: sVt[d][t]
#pragma unroll
    for (int i = 0; i < 4; ++i) {
      int c = tid + i * 256;
      int t = c >> 4, d0 = (c & 15) * 4;
      s16x4 vv = *(const s16x4*)&Vb[(kt * 64 + t) * 64 + d0];
#pragma unroll
      for (int u = 0; u < 4; ++u) sVt[(d0 + u) * 72 + t] = vv[u];
    }
    __syncthreads();

    // S = Q K^T (D=64 -> 2 MFMA k-steps), 4 n-tiles of 16 k-cols
    f32x4 s[4];
#pragma unroll
    for (int j = 0; j < 4; ++j) {
      s16x8 kf0 = *(const s16x8*)&sK[(j * 16 + ln15) * 72 + quad * 8];
      s16x8 kf1 = *(const s16x8*)&sK[(j * 16 + ln15) * 72 + 32 + quad * 8];
      f32x4 z = {};
      z = mfma_bf16(qf0, kf0, z);
      z = mfma_bf16(qf1, kf1, z);
      s[j] = z;
    }

    float sc[4][4];
    const int qrow = q0 + wid * 16 + quad * 4;  // + r
    const bool diag = (kt == qt);
#pragma unroll
    for (int j = 0; j < 4; ++j) {
      int kcol = kt * 64 + j * 16 + ln15;
#pragma unroll
      for (int r = 0; r < 4; ++r) {
        float v = s[j][r] * 0.125f;  // 1/sqrt(64)
        if (diag && kcol > qrow + r) v = -1e30f;
        sc[j][r] = v;
      }
    }
    // row-max across the 16 lanes of the quad (rows quad*4+r)
    float mx[4];
#pragma unroll
    for (int r = 0; r < 4; ++r)
      mx[r] = fmaxf(fmaxf(sc[0][r], sc[1][r]), fmaxf(sc[2][r], sc[3][r]));
#pragma unroll
    for (int off = 1; off < 16; off <<= 1)
#pragma unroll
      for (int r = 0; r < 4; ++r)
        mx[r] = fmaxf(mx[r], __shfl_xor(mx[r], off, 16));
    float alpha[4];
#pragma unroll
    for (int r = 0; r < 4; ++r) {
      float mnew = fmaxf(mrun[r], mx[r]);
      alpha[r] = __expf(mrun[r] - mnew);
      mrun[r] = mnew;
    }
    float p[4][4], rs[4] = {0.f, 0.f, 0.f, 0.f};
#pragma unroll
    for (int j = 0; j < 4; ++j)
#pragma unroll
      for (int r = 0; r < 4; ++r) {
        p[j][r] = __expf(sc[j][r] - mrun[r]);
        rs[r] += p[j][r];
      }
#pragma unroll
    for (int off = 1; off < 16; off <<= 1)
#pragma unroll
      for (int r = 0; r < 4; ++r)
        rs[r] += __shfl_xor(rs[r], off, 16);
#pragma unroll
    for (int r = 0; r < 4; ++r) lrun[r] = lrun[r] * alpha[r] + rs[r];

    // P: C-layout -> LDS -> A-layout round trip (m120 pattern)
#pragma unroll
    for (int j = 0; j < 4; ++j)
#pragma unroll
      for (int r = 0; r < 4; ++r)
        sPw[(quad * 4 + r) * 72 + j * 16 + ln15] = f2b(p[j][r]);
#pragma unroll
    for (int j = 0; j < 4; ++j)
#pragma unroll
      for (int r = 0; r < 4; ++r)
        o[j][r] *= alpha[r];
    __syncthreads();

    // O += P V  (k = t within tile, 2 k-steps; n-tiles over d)
    s16x8 pf0 = *(const s16x8*)&sPw[ln15 * 72 + quad * 8];
    s16x8 pf1 = *(const s16x8*)&sPw[ln15 * 72 + 32 + quad * 8];
#pragma unroll
    for (int j = 0; j < 4; ++j) {
      s16x8 vf0 = *(const s16x8*)&sVt[(j * 16 + ln15) * 72 + quad * 8];
      s16x8 vf1 = *(const s16x8*)&sVt[(j * 16 + ln15) * 72 + 32 + quad * 8];
      o[j] = mfma_bf16(pf0, vf0, o[j]);
      o[j] = mfma_bf16(pf1, vf1, o[j]);
    }
  }

  // epilogue: attn_out [B, T, C] bf16, col = h*64 + d
  const int b = bh >> 4, h = bh & 15;
#pragma unroll
  for (int r = 0; r < 4; ++r) {
    float inv = 1.f / lrun[r];
    int qg = q0 + wid * 16 + quad * 4 + r;
#pragma unroll
    for (int j = 0; j < 4; ++j)
      Aout[((size_t)b * 2048 + qg) * 1024 + h * 64 + j * 16 + ln15] =
          f2b(o[j][r] * inv);
  }
}

extern "C" void kernel_launch(void* const* d_in, const int* in_sizes, int n_in,
                              void* d_out, int out_size, void* d_ws, size_t ws_size,
                              hipStream_t stream) {
  const float* x  = (const float*)d_in[0];
  const float* wq = (const float*)d_in[1];
  const float* wk = (const float*)d_in[2];
  const float* wv = (const float*)d_in[3];
  const float* wo = (const float*)d_in[4];
  char* ws = (char*)d_ws;
  // ws layout (bytes): [0,16M) xb (reused as attn_out after QKV GEMM),
  // [16M, 22.3M) Wqkv bf16, [22.3M, 24.4M) Wo bf16, [24M..75.5M) Q|K|V bf16
  short* xb    = (short*)(ws);
  short* wqkvb = (short*)(ws + 16777216);
  short* wob   = (short*)(ws + 23068672);
  short* qkv   = (short*)(ws + 25165824);
  short* attn  = xb;  // x is dead after the QKV GEMM

  convert_all<<<12288, 256, 0, stream>>>(x, wq, wk, wv, wo, xb, wqkvb, wob);
  // QKV: M=8192, N=3072, K=1024
  gemm_bt<0><<<dim3(24, 64), 256, 0, stream>>>(xb, wqkvb, nullptr, qkv,
                                               8192, 3072, 1024);
  attn_fa<<<dim3(32, 64), 256, 0, stream>>>(qkv, qkv + 8388608,
                                            qkv + 16777216, attn);
  // out-proj: M=8192, N=1024, K=1024, fp32 out
  gemm_bt<1><<<dim3(8, 64), 256, 0, stream>>>(attn, wob, (float*)d_out, nullptr,
                                              8192, 1024, 1024);
}

// Round 2
// 326.136 us; speedup vs baseline: 1.5942x; 1.5942x over previous
//
#include <hip/hip_runtime.h>

typedef __attribute__((ext_vector_type(8))) short s16x8;
typedef __attribute__((ext_vector_type(4))) short s16x4;
typedef __attribute__((ext_vector_type(4))) float f32x4;
typedef __attribute__((ext_vector_type(8))) __bf16 bf16x8;
typedef __attribute__((ext_vector_type(2))) unsigned long long u64x2;

// fp32 -> bf16 round-to-nearest-even
__device__ __forceinline__ short f2b(float f) {
  unsigned u = __float_as_uint(f);
  u += 0x7fffu + ((u >> 16) & 1u);
  return (short)(u >> 16);
}

__device__ __forceinline__ f32x4 mfma32(s16x8 a, s16x8 b, f32x4 c) {
  return __builtin_amdgcn_mfma_f32_16x16x32_bf16(
      __builtin_bit_cast(bf16x8, a), __builtin_bit_cast(bf16x8, b), c, 0, 0, 0);
}

#if __has_builtin(__builtin_amdgcn_mfma_f32_16x16x16bf16_1k)
#define HAVE_MFMA16 1
__device__ __forceinline__ f32x4 mfma16(s16x4 a, s16x4 b, f32x4 c) {
  return __builtin_amdgcn_mfma_f32_16x16x16bf16_1k(a, b, c, 0, 0, 0);
}
#else
#define HAVE_MFMA16 0
// repack P (S^T C-layout regs, k=16j+quad*4+r) into 16x16x32 A-frag (k=quad*8+c)
__device__ __forceinline__ s16x8 repack(s16x4 pa, s16x4 pb, int quad, int ln15) {
  unsigned long long a = __builtin_bit_cast(unsigned long long, pa);
  unsigned long long bq = __builtin_bit_cast(unsigned long long, pb);
  int srcLo = ((quad & 1) << 5) | ln15;
  unsigned long long loa = __shfl(a, srcLo);
  unsigned long long lob = __shfl(bq, srcLo);
  unsigned long long hia = __shfl(a, srcLo + 16);
  unsigned long long hib = __shfl(bq, srcLo + 16);
  u64x2 t;
  t[0] = quad < 2 ? loa : lob;
  t[1] = quad < 2 ? hia : hib;
  return __builtin_bit_cast(s16x8, t);
}
#endif

// ---------------- convert fp32 -> bf16 (x, Wq|Wk|Wv concat, Wo) ----------------
__global__ __launch_bounds__(256) void convert_all(
    const float* __restrict__ x, const float* __restrict__ wq,
    const float* __restrict__ wk, const float* __restrict__ wv,
    const float* __restrict__ wo, short* __restrict__ xb,
    short* __restrict__ wqkvb, short* __restrict__ wob) {
  size_t i4 = ((size_t)blockIdx.x * 256 + threadIdx.x) * 4;
  const float* src;
  short* dst;
  size_t off;
  if (i4 < 8388608) {
    src = x; dst = xb; off = i4;
  } else if (i4 < 9437184) {
    src = wq; dst = wqkvb; off = i4 - 8388608;
  } else if (i4 < 10485760) {
    src = wk; dst = wqkvb + 1048576; off = i4 - 9437184;
  } else if (i4 < 11534336) {
    src = wv; dst = wqkvb + 2097152; off = i4 - 10485760;
  } else {
    src = wo; dst = wob; off = i4 - 11534336;
  }
  float4 f = *(const float4*)(src + off);
  s16x4 o;
  o[0] = f2b(f.x); o[1] = f2b(f.y); o[2] = f2b(f.z); o[3] = f2b(f.w);
  *(s16x4*)(dst + off) = o;
}

// ---------------- GEMM: C[M,N] = A[M,K] * B[N,K]^T  (m97 structure) ----------
__device__ __forceinline__ void stage_tile(const short* __restrict__ g, int ld,
                                           int row0, int k0, short* lds,
                                           int wid, int lane) {
#pragma unroll
  for (int i = 0; i < 2; ++i) {
    int e = i * 2048 + wid * 512 + lane * 8;
    int row = e >> 5, col = e & 31;
    const short* gp = g + (size_t)(row0 + row) * ld + k0 + col;
    __builtin_amdgcn_global_load_lds(
        (const __attribute__((address_space(1))) void*)gp,
        (__attribute__((address_space(3))) void*)(lds + i * 2048 + wid * 512),
        16, 0, 0);
  }
}

template <int EPI>  // 0 = scatter QKV bf16 [3][B,H,T,D]; 1 = fp32 direct store
__global__ __launch_bounds__(256) void gemm_bt(
    const short* __restrict__ A, const short* __restrict__ Bw,
    float* __restrict__ outf, short* __restrict__ qkv,
    int M, int N, int K) {
  __shared__ __align__(16) short lA[128 * 32];
  __shared__ __align__(16) short lB[128 * 32];
  const int tid = threadIdx.x;
  const int lane = tid & 63, wid = tid >> 6;
  const int quad = lane >> 4, ln15 = lane & 15;
  const int wm = wid & 1, wn = wid >> 1;
  const int m0 = blockIdx.y * 128, n0 = blockIdx.x * 128;

  f32x4 acc[4][4] = {};

  stage_tile(A, K, m0, 0, lA, wid, lane);
  stage_tile(Bw, K, n0, 0, lB, wid, lane);

  const int nk = K >> 5;
  for (int kt = 0; kt < nk; ++kt) {
    __syncthreads();
    s16x8 af[4], bf[4];
#pragma unroll
    for (int i = 0; i < 4; ++i)
      af[i] = *(const s16x8*)&lA[(wm * 64 + i * 16 + ln15) * 32 + quad * 8];
#pragma unroll
    for (int j = 0; j < 4; ++j)
      bf[j] = *(const s16x8*)&lB[(wn * 64 + j * 16 + ln15) * 32 + quad * 8];
#pragma unroll
    for (int i = 0; i < 4; ++i)
#pragma unroll
      for (int j = 0; j < 4; ++j)
        acc[i][j] = mfma32(af[i], bf[j], acc[i][j]);
    __syncthreads();
    if (kt + 1 < nk) {
      stage_tile(A, K, m0, (kt + 1) << 5, lA, wid, lane);
      stage_tile(Bw, K, n0, (kt + 1) << 5, lB, wid, lane);
    }
  }

#pragma unroll
  for (int i = 0; i < 4; ++i)
#pragma unroll
    for (int j = 0; j < 4; ++j)
#pragma unroll
      for (int r = 0; r < 4; ++r) {
        int m = m0 + wm * 64 + i * 16 + quad * 4 + r;
        int n = n0 + wn * 64 + j * 16 + ln15;
        float v = acc[i][j][r];
        if (EPI == 1) {
          outf[(size_t)m * N + n] = v;
        } else {
          int b = m >> 11, t = m & 2047;
          int which = n >> 10, rem = n & 1023;
          int h = rem >> 6, d = rem & 63;
          qkv[(size_t)which * 8388608 +
              (size_t)((((b << 4) + h) << 11) + t) * 64 + d] = f2b(v);
        }
      }
}

// ---------------- flash attention, S^T formulation ---------------------------
// 4 waves, 128 q rows/block (32/wave = 2 q-frags). K-tile 64.
// S^T = K Q^T: C-layout -> q on lane&15, k on quad*4+r  => 2-shfl row reduce,
// and P regs directly usable as 16x16x16 A-operand (k=quad*4+i). No P LDS trip.
// V double-buffered in LDS transposed [d][t+pad72]; conflict-free b32 writes.
// Balanced pairing: block does q-tiles (a, 15-a) => uniformly 34 k-tiles.
__device__ __forceinline__ void softmax_step(
    f32x4 s[4], s16x4 pk[4], f32x4 o[4], float& mrun, float& lrun,
    int qg, int kt, bool domask, int quad, int ln15) {
  const float SC = 0.18033688f;  // (1/8) * log2(e); exp via exp2
  float v[4][4];
  float mx = -3e38f;
#pragma unroll
  for (int jm = 0; jm < 4; ++jm)
#pragma unroll
    for (int r = 0; r < 4; ++r) {
      float t = s[jm][r] * SC;
      if (domask) {
        int kg = kt * 64 + jm * 16 + quad * 4 + r;
        if (kg > qg) t = -3e38f;
      }
      v[jm][r] = t;
      mx = fmaxf(mx, t);
    }
  mx = fmaxf(mx, __shfl_xor(mx, 16));
  mx = fmaxf(mx, __shfl_xor(mx, 32));
  float mnew = fmaxf(mrun, mx);
  float aw = exp2f(mrun - mnew);
  mrun = mnew;
  float rs = 0.f;
#pragma unroll
  for (int jm = 0; jm < 4; ++jm) {
    s16x4 pq;
#pragma unroll
    for (int r = 0; r < 4; ++r) {
      float p = exp2f(v[jm][r] - mnew);
      rs += p;
      pq[r] = f2b(p);
    }
    pk[jm] = pq;
  }
  rs += __shfl_xor(rs, 16);
  rs += __shfl_xor(rs, 32);
  lrun = lrun * aw + rs;
#pragma unroll
  for (int r = 0; r < 4; ++r) {
    float ar = __shfl(aw, quad * 4 + r, 16);
#pragma unroll
    for (int jd = 0; jd < 4; ++jd) o[jd][r] *= ar;
  }
}

__global__ __launch_bounds__(256, 3) void attn_fa(
    const short* __restrict__ Q, const short* __restrict__ K,
    const short* __restrict__ V, short* __restrict__ Aout) {
  __shared__ __align__(16) short sVt[2][64 * 72];
  const int tid = threadIdx.x;
  const int lane = tid & 63, wid = tid >> 6;
  const int quad = lane >> 4, ln15 = lane & 15;
  const int bh = blockIdx.y;
  const short* Qb = Q + (size_t)bh * 131072;
  const short* Kb = K + (size_t)bh * 131072;
  const short* Vb = V + (size_t)bh * 131072;
  const int b = bh >> 4, h = bh & 15;
  const int tp = tid & 31, dgrp = tid >> 5;  // V staging: t0=2*tp, d0=dgrp*4

  for (int pass = 0; pass < 2; ++pass) {
    const int qt = pass ? 15 - (int)blockIdx.x : (int)blockIdx.x;
    const int qw = qt * 128 + wid * 32;
    s16x8 qf[2][2];
#pragma unroll
    for (int qo = 0; qo < 2; ++qo)
#pragma unroll
      for (int ks = 0; ks < 2; ++ks)
        qf[qo][ks] =
            *(const s16x8*)&Qb[(qw + qo * 16 + ln15) * 64 + ks * 32 + quad * 8];

    f32x4 o0[4] = {}, o1[4] = {};
    float m0 = -3e38f, l0 = 0.f, m1 = -3e38f, l1 = 0.f;

    __syncthreads();  // protect buffers from previous pass's readers
    // prologue: stage V tile 0 -> buf 0
#pragma unroll
    for (int i = 0; i < 2; ++i) {
      int d0 = dgrp * 4 + i * 32;
      s16x4 va = *(const s16x4*)&Vb[(2 * tp) * 64 + d0];
      s16x4 vb = *(const s16x4*)&Vb[(2 * tp + 1) * 64 + d0];
#pragma unroll
      for (int u = 0; u < 4; ++u) {
        unsigned w = (unsigned)(unsigned short)va[u] |
                     ((unsigned)(unsigned short)vb[u] << 16);
        *(unsigned*)&sVt[0][(d0 + u) * 72 + 2 * tp] = w;
      }
    }

    const int nt = 2 * qt + 2;
    for (int kt = 0; kt < nt; ++kt) {
      __syncthreads();
      const short* bufc = sVt[kt & 1];
      // prefetch next V tile into regs (hide global latency under compute)
      s16x4 va[2], vb[2];
      const bool nxt = (kt + 1 < nt);
      if (nxt) {
#pragma unroll
        for (int i = 0; i < 2; ++i) {
          int d0 = dgrp * 4 + i * 32;
          va[i] = *(const s16x4*)&Vb[((kt + 1) * 64 + 2 * tp) * 64 + d0];
          vb[i] = *(const s16x4*)&Vb[((kt + 1) * 64 + 2 * tp + 1) * 64 + d0];
        }
      }
      // ---- S^T = K Q^T ----
      f32x4 s0[4] = {}, s1[4] = {};
#pragma unroll
      for (int jm = 0; jm < 4; ++jm) {
        const short* kp = &Kb[(size_t)(kt * 64 + jm * 16 + ln15) * 64 + quad * 8];
        s16x8 k0 = *(const s16x8*)kp;
        s16x8 k1 = *(const s16x8*)(kp + 32);
        s0[jm] = mfma32(k0, qf[0][0], s0[jm]);
        s0[jm] = mfma32(k1, qf[0][1], s0[jm]);
        s1[jm] = mfma32(k0, qf[1][0], s1[jm]);
        s1[jm] = mfma32(k1, qf[1][1], s1[jm]);
      }
      // ---- online softmax ----
      const bool domask = (kt >= 2 * qt);
      s16x4 pk0[4], pk1[4];
      softmax_step(s0, pk0, o0, m0, l0, qw + ln15, kt, domask, quad, ln15);
      softmax_step(s1, pk1, o1, m1, l1, qw + 16 + ln15, kt, domask, quad, ln15);
      // ---- O += P V ----
#if HAVE_MFMA16
#pragma unroll
      for (int js = 0; js < 4; ++js)
#pragma unroll
        for (int jd = 0; jd < 4; ++jd) {
          s16x4 vf =
              *(const s16x4*)&bufc[(jd * 16 + ln15) * 72 + js * 16 + quad * 4];
          o0[jd] = mfma16(pk0[js], vf, o0[jd]);
          o1[jd] = mfma16(pk1[js], vf, o1[jd]);
        }
#else
#pragma unroll
      for (int ks = 0; ks < 2; ++ks) {
        s16x8 a0 = repack(pk0[2 * ks], pk0[2 * ks + 1], quad, ln15);
        s16x8 a1 = repack(pk1[2 * ks], pk1[2 * ks + 1], quad, ln15);
#pragma unroll
        for (int jd = 0; jd < 4; ++jd) {
          s16x8 vf =
              *(const s16x8*)&bufc[(jd * 16 + ln15) * 72 + ks * 32 + quad * 8];
          o0[jd] = mfma32(a0, vf, o0[jd]);
          o1[jd] = mfma32(a1, vf, o1[jd]);
        }
      }
#endif
      // write prefetched tile -> other buffer (conflict-free b32 writes)
      if (nxt) {
        short* bufn = sVt[(kt + 1) & 1];
#pragma unroll
        for (int i = 0; i < 2; ++i) {
          int d0 = dgrp * 4 + i * 32;
#pragma unroll
          for (int u = 0; u < 4; ++u) {
            unsigned w = (unsigned)(unsigned short)va[i][u] |
                         ((unsigned)(unsigned short)vb[i][u] << 16);
            *(unsigned*)&bufn[(d0 + u) * 72 + 2 * tp] = w;
          }
        }
      }
    }
    // epilogue: O rows q=quad*4+r (C-layout), cols d=jd*16+ln15
#pragma unroll
    for (int qo = 0; qo < 2; ++qo) {
      f32x4* o = qo ? o1 : o0;
      float l = qo ? l1 : l0;
#pragma unroll
      for (int r = 0; r < 4; ++r) {
        float lv = __shfl(l, quad * 4 + r, 16);
        float linv = 1.f / lv;
        int qg = qw + qo * 16 + quad * 4 + r;
        size_t row = ((size_t)b * 2048 + qg) * 1024 + h * 64;
#pragma unroll
        for (int jd = 0; jd < 4; ++jd)
          Aout[row + jd * 16 + ln15] = f2b(o[jd][r] * linv);
      }
    }
  }
}

extern "C" void kernel_launch(void* const* d_in, const int* in_sizes, int n_in,
                              void* d_out, int out_size, void* d_ws, size_t ws_size,
                              hipStream_t stream) {
  const float* x  = (const float*)d_in[0];
  const float* wq = (const float*)d_in[1];
  const float* wk = (const float*)d_in[2];
  const float* wv = (const float*)d_in[3];
  const float* wo = (const float*)d_in[4];
  char* ws = (char*)d_ws;
  short* xb    = (short*)(ws);
  short* wqkvb = (short*)(ws + 16777216);
  short* wob   = (short*)(ws + 23068672);
  short* qkv   = (short*)(ws + 25165824);
  short* attn  = xb;  // x dead after QKV GEMM

  convert_all<<<12288, 256, 0, stream>>>(x, wq, wk, wv, wo, xb, wqkvb, wob);
  gemm_bt<0><<<dim3(24, 64), 256, 0, stream>>>(xb, wqkvb, nullptr, qkv,
                                               8192, 3072, 1024);
  attn_fa<<<dim3(8, 64), 256, 0, stream>>>(qkv, qkv + 8388608,
                                           qkv + 16777216, attn);
  gemm_bt<1><<<dim3(8, 64), 256, 0, stream>>>(attn, wob, (float*)d_out, nullptr,
                                              8192, 1024, 1024);
}